// Round 14
// baseline (189.840 us; speedup 1.0000x reference)
//
#include <hip/hip_runtime.h>
#include <hip/hip_bf16.h>
#include <cstdint>
#include <math.h>

// ---------------------------------------------------------------------------
// MyMultiHeadAttention: cvt -> q/k/v proj (256x128 tile, BK=32, 3-buf
// depth-2 counted vmcnt, 72 KiB LDS => 2 blocks/CU, grid=768) -> fused flash
// attention (UNPAIRED 128-row q-blocks, LPT order, 8 waves, swapped QK^T,
// in-register softmax+P, exact -1e9 semantics) -> output proj (256x128 BK=64,
// grid=256).  B=8 S=1024 D=1024 H=16 Dh=64.
// ---------------------------------------------------------------------------

typedef __bf16 bf16_t;
typedef __bf16 bf16x8 __attribute__((ext_vector_type(8)));
typedef __bf16 bf16x4 __attribute__((ext_vector_type(4)));
typedef float  f32x4  __attribute__((ext_vector_type(4)));

#define MFMA16(a, b, c) __builtin_amdgcn_mfma_f32_16x16x32_bf16((a), (b), (c), 0, 0, 0)
#define NEGV (-1e9f)

__device__ __forceinline__ void gl_lds16(const void* gp, void* lp) {
  __builtin_amdgcn_global_load_lds(
      (__attribute__((address_space(1))) void*)(gp),
      (__attribute__((address_space(3))) void*)(lp), 16, 0, 0);
}

// raw barrier with compiler memory fences
__device__ __forceinline__ void bar() {
  asm volatile("" ::: "memory");
  __builtin_amdgcn_s_barrier();
  asm volatile("" ::: "memory");
}

__device__ __forceinline__ unsigned int pk2(float lo, float hi) {
  unsigned short a = __builtin_bit_cast(unsigned short, (bf16_t)lo);
  unsigned short b = __builtin_bit_cast(unsigned short, (bf16_t)hi);
  return (unsigned int)a | ((unsigned int)b << 16);
}

// ---------------- f32 -> bf16 bulk convert, single launch -------------------
__device__ __forceinline__ void cvt_body(const float* __restrict__ in,
                                         bf16_t* __restrict__ out, int i) {
  const float4* p = reinterpret_cast<const float4*>(in) + (size_t)i * 2;
  float4 a = p[0], b = p[1];
  bf16x8 r = {(bf16_t)a.x, (bf16_t)a.y, (bf16_t)a.z, (bf16_t)a.w,
              (bf16_t)b.x, (bf16_t)b.y, (bf16_t)b.z, (bf16_t)b.w};
  *reinterpret_cast<bf16x8*>(out + (size_t)i * 8) = r;
}

__global__ __launch_bounds__(256) void cvt_all(
    const float* __restrict__ q, const float* __restrict__ k, const float* __restrict__ v,
    const float* __restrict__ wq, const float* __restrict__ wk,
    const float* __restrict__ wv, const float* __restrict__ wo,
    bf16_t* __restrict__ oq, bf16_t* __restrict__ ok, bf16_t* __restrict__ ov,
    bf16_t* __restrict__ owq, bf16_t* __restrict__ owk,
    bf16_t* __restrict__ owv, bf16_t* __restrict__ owo) {
  const int bid = (int)blockIdx.x;
  if (bid < 12288) {
    const int s = bid >> 12;
    const int i = (bid & 4095) * 256 + (int)threadIdx.x;
    cvt_body(s == 0 ? q : (s == 1 ? k : v),
             s == 0 ? oq : (s == 1 ? ok : ov), i);
  } else {
    const int r = bid - 12288;
    const int s = r >> 9;
    const int i = (r & 511) * 256 + (int)threadIdx.x;
    cvt_body(s == 0 ? wq : (s == 1 ? wk : (s == 2 ? wv : wo)),
             s == 0 ? owq : (s == 1 ? owk : (s == 2 ? owv : owo)), i);
  }
}

// ============ q/k/v GEMM: 256x128 tile, BK=32, 2 blocks/CU (r13) ============
__global__ __launch_bounds__(512, 4) void gemm_qkv(const bf16_t* __restrict__ qbf,
                                                   const bf16_t* __restrict__ kbf,
                                                   const bf16_t* __restrict__ vbf,
                                                   const bf16_t* __restrict__ wqb,
                                                   const bf16_t* __restrict__ wkb,
                                                   const bf16_t* __restrict__ wvb,
                                                   const float* __restrict__ bq,
                                                   const float* __restrict__ bv,
                                                   bf16_t* __restrict__ qp,
                                                   bf16_t* __restrict__ kp,
                                                   bf16_t* __restrict__ vtw) {
  __shared__ __align__(16) char lds[73728];  // A 3x16K @0, B 3x8K @49152
  const int bid = (int)blockIdx.x;
  const int z = bid >> 8;
  const int idx = bid & 255;
  const int p = ((idx >> 6) << 3) | (idx & 7);
  const int n = (idx >> 3) & 7;
  const bf16_t* A = z == 0 ? qbf : (z == 1 ? kbf : vbf);
  const bf16_t* W = z == 0 ? wqb : (z == 1 ? wkb : wvb);
  const int t = threadIdx.x;
  const int w = t >> 6, l = t & 63, lr = l & 15, lg = l >> 4;
  const int wr = w >> 1, wc = w & 1;
  const int m0 = p * 256, n0 = n * 128;
  const int K = 1024, N = 1024;

  const int gc = (t & 3) ^ ((t >> 3) & 3);
  const bf16_t* Ag = A + (size_t)(m0 + (t >> 2)) * K + gc * 8;
  const bf16_t* Wg = W + (size_t)(n0 + (t >> 2)) * K + gc * 8;

  auto stageA = [&](int buf, int tile) {
    char* dst = lds + buf * 16384 + t * 16;
    const size_t kt = (size_t)tile * 32;
    gl_lds16(Ag + kt,                   dst);
    gl_lds16(Ag + kt + (size_t)128 * K, dst + 8192);
  };
  auto stageB = [&](int buf, int tile) {
    gl_lds16(Wg + (size_t)tile * 32, lds + 49152 + buf * 8192 + t * 16);
  };

  stageA(0, 0); stageB(0, 0); stageA(1, 1); stageB(1, 1);
  asm volatile("s_waitcnt vmcnt(3)" ::: "memory");
  bar();

  f32x4 acc[4][4] = {};
  const int cofs = (lg ^ ((lr >> 1) & 3)) << 4;

  for (int T = 0; T < 32; ++T) {
    const int cur = T % 3;
    const char* Ab = lds + cur * 16384;
    const char* Bb = lds + 49152 + cur * 8192;
    bf16x8 af[4], bfr[4];
#pragma unroll
    for (int mt = 0; mt < 4; mt++)
      af[mt] = *(const bf16x8*)(Ab + (wr * 64 + mt * 16 + lr) * 64 + cofs);
#pragma unroll
    for (int nt = 0; nt < 4; nt++)
      bfr[nt] = *(const bf16x8*)(Bb + (wc * 64 + nt * 16 + lr) * 64 + cofs);
    if (T + 2 < 32) { stageA((T + 2) % 3, T + 2); stageB((T + 2) % 3, T + 2); }
    if (T < 30)       asm volatile("s_waitcnt vmcnt(3)" ::: "memory");
    else if (T == 30) asm volatile("s_waitcnt vmcnt(0)" ::: "memory");
    bar();
    asm volatile("s_waitcnt lgkmcnt(0)" ::: "memory");
    __builtin_amdgcn_s_setprio(1);
#pragma unroll
    for (int mt = 0; mt < 4; mt++)
#pragma unroll
      for (int nt = 0; nt < 4; nt++)
        acc[mt][nt] = MFMA16(af[mt], bfr[nt], acc[mt][nt]);
    __builtin_amdgcn_s_setprio(0);
    bar();
  }

  if (z != 2) {
    bf16_t* outp = (z == 0) ? qp : kp;
    const float sc = (z == 0) ? 0.125f : 1.0f;  // fold attention's /8 (exact)
#pragma unroll
    for (int nt = 0; nt < 4; nt++) {
      const int col = n0 + wc * 64 + nt * 16 + lr;
      const float bb = (z == 0) ? bq[col] : 0.0f;
#pragma unroll
      for (int mt = 0; mt < 4; mt++)
#pragma unroll
        for (int i = 0; i < 4; i++) {
          const int row = m0 + wr * 64 + mt * 16 + lg * 4 + i;
          outp[(size_t)row * N + col] = (bf16_t)((acc[mt][nt][i] + bb) * sc);
        }
    }
  } else {
    __syncthreads();
    char* Tl = lds;
#pragma unroll
    for (int nt = 0; nt < 4; nt++) {
      const int col_l = wc * 64 + nt * 16 + lr;
      const float bb = bv[n0 + col_l];
#pragma unroll
      for (int mt = 0; mt < 4; mt++)
#pragma unroll
        for (int i = 0; i < 4; i++) {
          const int row_l = wr * 64 + mt * 16 + lg * 4 + i;
          *(bf16_t*)(Tl + col_l * 512 + ((row_l * 2) ^ ((col_l & 7) << 4))) =
              (bf16_t)(acc[mt][nt][i] + bb);
        }
    }
    __syncthreads();
    const int b = m0 >> 10, s0 = m0 & 1023;
    const int c_l = t >> 2, sub = t & 3;
    bf16_t* dst = vtw + (size_t)(b * 1024 + n0 + c_l) * 1024 + s0 + sub * 64;
    const char* Trow = Tl + c_l * 512;
    const int sw2 = (c_l & 7) << 4;
#pragma unroll
    for (int jj = 0; jj < 8; jj++) {
      const int lc = sub * 8 + jj;
      bf16x8 vv = *(const bf16x8*)(Trow + ((lc << 4) ^ sw2));
      *(bf16x8*)(dst + jj * 8) = vv;
    }
  }
}

// ---------------- final GEMM: f32 out, 256x128 BK=64, 3-buf (r11) ----------
__global__ __launch_bounds__(512) void gemm_out(const bf16_t* __restrict__ A,
                                                const bf16_t* __restrict__ W,
                                                const float* __restrict__ bias,
                                                float* __restrict__ outp) {
  __shared__ __align__(16) char lds[147456];  // A 3x32K + B 3x16K
  const int bid = (int)blockIdx.x;
  const int p = ((bid >> 6) << 3) | (bid & 7);
  const int n = (bid >> 3) & 7;
  const int t = threadIdx.x;
  const int w = t >> 6, l = t & 63, lr = l & 15, lg = l >> 4;
  const int wr = w >> 1, wc = w & 1;
  const int m0 = p * 256, n0 = n * 128;
  const int K = 1024, N = 1024;

  const int gc = (t & 7) ^ ((t >> 3) & 7);
  const bf16_t* Ag = A + (size_t)(m0 + (t >> 3)) * K + gc * 8;
  const bf16_t* Wg = W + (size_t)(n0 + (t >> 3)) * K + gc * 8;

  auto stageA = [&](int buf, int tile) {
    char* dst = lds + buf * 32768 + t * 16;
    const size_t kt = (size_t)tile * 64;
    gl_lds16(Ag + kt,                    dst);
    gl_lds16(Ag + kt + (size_t)64 * K,   dst + 8192);
    gl_lds16(Ag + kt + (size_t)128 * K,  dst + 16384);
    gl_lds16(Ag + kt + (size_t)192 * K,  dst + 24576);
  };
  auto stageB = [&](int buf, int tile) {
    char* dst = lds + 98304 + buf * 16384 + t * 16;
    const size_t kt = (size_t)tile * 64;
    gl_lds16(Wg + kt,                    dst);
    gl_lds16(Wg + kt + (size_t)64 * K,   dst + 8192);
  };
  stageA(0, 0); stageB(0, 0); stageA(1, 1); stageB(1, 1);
  asm volatile("s_waitcnt vmcnt(6)" ::: "memory");
  bar();

  f32x4 acc[4][4] = {};
  const int xorv = (lr & 7) << 4;
  const int k0o = lg * 16, k1o = 64 + lg * 16;

  for (int T = 0; T < 16; ++T) {
    const int cur = T % 3;
    const char* Ab = lds + cur * 32768;
    const char* Bb = lds + 98304 + cur * 16384;
    bf16x8 af[4][2], b0[2][2], b1[2][2];
#pragma unroll
    for (int mt = 0; mt < 4; mt++) {
      const int row = wr * 64 + mt * 16 + lr;
      af[mt][0] = *(const bf16x8*)(Ab + row * 128 + (k0o ^ xorv));
      af[mt][1] = *(const bf16x8*)(Ab + row * 128 + (k1o ^ xorv));
    }
#pragma unroll
    for (int nt = 0; nt < 2; nt++) {
      const int row = wc * 64 + nt * 16 + lr;
      b0[nt][0] = *(const bf16x8*)(Bb + row * 128 + (k0o ^ xorv));
      b0[nt][1] = *(const bf16x8*)(Bb + row * 128 + (k1o ^ xorv));
    }
    if (T + 2 < 16) stageA((T + 2) % 3, T + 2);
    bar();
    asm volatile("s_waitcnt lgkmcnt(0)" ::: "memory");
    __builtin_amdgcn_s_setprio(1);
#pragma unroll
    for (int mt = 0; mt < 4; mt++)
#pragma unroll
      for (int nt = 0; nt < 2; nt++) {
        acc[mt][nt] = MFMA16(af[mt][0], b0[nt][0], acc[mt][nt]);
        acc[mt][nt] = MFMA16(af[mt][1], b0[nt][1], acc[mt][nt]);
      }
    __builtin_amdgcn_s_setprio(0);
    bar();
#pragma unroll
    for (int nt = 0; nt < 2; nt++) {
      const int row = wc * 64 + (nt + 2) * 16 + lr;
      b1[nt][0] = *(const bf16x8*)(Bb + row * 128 + (k0o ^ xorv));
      b1[nt][1] = *(const bf16x8*)(Bb + row * 128 + (k1o ^ xorv));
    }
    if (T + 2 < 16) stageB((T + 2) % 3, T + 2);
    if (T < 14)       asm volatile("s_waitcnt vmcnt(6)" ::: "memory");
    else if (T == 14) asm volatile("s_waitcnt vmcnt(0)" ::: "memory");
    bar();
    asm volatile("s_waitcnt lgkmcnt(0)" ::: "memory");
    __builtin_amdgcn_s_setprio(1);
#pragma unroll
    for (int mt = 0; mt < 4; mt++)
#pragma unroll
      for (int nt = 0; nt < 2; nt++) {
        acc[mt][nt + 2] = MFMA16(af[mt][0], b1[nt][0], acc[mt][nt + 2]);
        acc[mt][nt + 2] = MFMA16(af[mt][1], b1[nt][1], acc[mt][nt + 2]);
      }
    __builtin_amdgcn_s_setprio(0);
    bar();
  }

#pragma unroll
  for (int nt = 0; nt < 4; nt++) {
    const int col = n0 + wc * 64 + nt * 16 + lr;
    const float bb = bias[col];
#pragma unroll
    for (int mt = 0; mt < 4; mt++)
#pragma unroll
      for (int i = 0; i < 4; i++) {
        const int row = m0 + wr * 64 + mt * 16 + lg * 4 + i;
        outp[(size_t)row * N + col] = acc[mt][nt][i] + bb;
      }
  }
}

// ---------------- in-register P pack + butterfly (16-lane groups) ----------
__device__ __forceinline__ void pack_bfly(const f32x4 (&s)[4], int lg,
                                          bf16x8& pbv0, bf16x8& pbv1) {
  unsigned int u[4][2], sh[4][2];
#pragma unroll
  for (int nt = 0; nt < 4; nt++) {
    u[nt][0] = pk2(s[nt][0], s[nt][1]);
    u[nt][1] = pk2(s[nt][2], s[nt][3]);
  }
#pragma unroll
  for (int nt = 0; nt < 4; nt++) {
    sh[nt][0] = (unsigned int)__shfl_xor((int)u[nt][0], 16, 64);
    sh[nt][1] = (unsigned int)__shfl_xor((int)u[nt][1], 16, 64);
  }
  const bool ev = (lg & 1) == 0;
  unsigned int Y[8];
  Y[0] = ev ? u[0][0] : sh[1][0];  Y[1] = ev ? u[0][1] : sh[1][1];
  Y[2] = ev ? u[2][0] : sh[3][0];  Y[3] = ev ? u[2][1] : sh[3][1];
  Y[4] = ev ? sh[0][0] : u[1][0];  Y[5] = ev ? sh[0][1] : u[1][1];
  Y[6] = ev ? sh[2][0] : u[3][0];  Y[7] = ev ? sh[2][1] : u[3][1];
  const bool mid = (lg == 1) || (lg == 2);
#pragma unroll
  for (int j = 0; j < 8; j++) {
    const unsigned int z = (unsigned int)__shfl_xor((int)Y[j], 48, 64);
    Y[j] = mid ? z : Y[j];
  }
  union U8 { unsigned int u[4]; bf16x8 v; };
  U8 p0, p1;
  p0.u[0] = Y[0]; p0.u[1] = Y[1]; p0.u[2] = Y[4]; p0.u[3] = Y[5];
  p1.u[0] = Y[2]; p1.u[1] = Y[3]; p1.u[2] = Y[6]; p1.u[3] = Y[7];
  pbv0 = p0.v;
  pbv1 = p1.v;
}

// ---------------- fused flash attention (unpaired 128-row q-blocks) --------
// Grid 1024.  L decode: bh = (L&7)+8*(L>>6) (bh%8 = XCD), j = 7-((L>>3)&7)
// (LPT: long blocks dispatch first).  Block j covers q rows [128j, 128j+128);
// 8 waves x 16 rows.  ktEnd = 2j+2 staged tiles (exact -1e9 degenerate
// fallback to 16 via ul).  Per-wave static skip beyond causal horizon;
// dynamic underflow skip + defer-max unchanged (bit-identical numerics).
__global__ __launch_bounds__(512, 8) void attn_fused(const bf16_t* __restrict__ qp,
                                                     const bf16_t* __restrict__ kp,
                                                     const bf16_t* __restrict__ vt,
                                                     const int* __restrict__ pad,
                                                     bf16_t* __restrict__ outp) {
  __shared__ bf16_t Ks[2][64 * 64];   // [key][dh], XOR-swizzled
  __shared__ bf16_t Vts[2][64 * 64];  // [dh][key], XOR-swizzled
  __shared__ int padI[1024];
  __shared__ int sf[8];
  const int t = threadIdx.x, w = t >> 6, l = t & 63, lr = l & 15, lg = l >> 4;
  const int L = (int)blockIdx.x;
  const int bh = (L & 7) + ((L >> 6) << 3);
  const int j = 7 - ((L >> 3) & 7);
  const int b = bh >> 4, h = bh & 15;
  const int q0 = j * 128;

  const int srow = t >> 3, sc = t & 7;
  const int gc = sc ^ (srow & 7);
  const bf16_t* kgb = kp + (size_t)(b * 1024 + srow) * 1024 + h * 64 + gc * 8;
  const bf16_t* vgb = vt + (size_t)(bh * 64 + srow) * 1024 + gc * 8;

  auto stage = [&](int bufi, int k0s) {
    gl_lds16(kgb + (size_t)k0s * 1024, (char*)(Ks[bufi]) + t * 16);
    gl_lds16(vgb + k0s,                (char*)(Vts[bufi]) + t * 16);
  };

  // degenerate-row check: any unpadded key in [0, q0]?
  bool un = false;
  for (int jj = t; jj <= q0; jj += 512) un |= (pad[b * 1024 + jj] == 0);
  const bool anyun = __any(un);
  if (l == 0) sf[w] = anyun ? 1 : 0;

  stage(0, 0);
  if (t < 256) gl_lds16(pad + b * 1024 + t * 4, (char*)padI + t * 16);

  const int base16 = q0 + w * 16;          // this wave's first q row
  const int qrow_l = base16 + lr;          // lane's q row
  const int myend = (base16 + 15) >> 6;    // last causally-needed k-tile
  const bf16_t* qg = qp + (size_t)(b * 1024 + qrow_l) * 1024 + h * 64 + lg * 8;
  const bf16x8 qa0 = *reinterpret_cast<const bf16x8*>(qg);
  const bf16x8 qa1 = *reinterpret_cast<const bf16x8*>(qg + 32);

  __syncthreads();  // sf ready; drains tile-0 staging + padI
  int ul = 0;
#pragma unroll
  for (int i = 0; i < 8; i++) ul |= sf[i];
  const int ktEnd = ul ? (2 * j + 2) : 16;

  f32x4 o[4] = {};
  float m_ = -INFINITY, ld_ = 0.0f;

  for (int kt = 0; kt < ktEnd; ++kt) {
    const int cur = kt & 1;
    if (kt + 1 < ktEnd) {
      stage(cur ^ 1, (kt + 1) * 64);
      asm volatile("s_waitcnt vmcnt(2)" ::: "memory");
    } else {
      asm volatile("s_waitcnt vmcnt(0)" ::: "memory");
    }
    __builtin_amdgcn_s_barrier();

    if (kt <= myend || !ul) {
      const char* Kb = (const char*)(Ks[cur]);
      const char* Vb = (const char*)(Vts[cur]);
      const int k0 = kt * 64;

      f32x4 s[4] = {};
#pragma unroll
      for (int nt = 0; nt < 4; nt++) {
        const int row = nt * 16 + lr;
        const int sw = (row & 7) << 4;
        bf16x8 kb0 = *reinterpret_cast<const bf16x8*>(Kb + row * 128 + ((lg * 16) ^ sw));
        bf16x8 kb1 = *reinterpret_cast<const bf16x8*>(Kb + row * 128 + ((lg * 16 + 64) ^ sw));
        s[nt] = MFMA16(kb0, qa0, s[nt]);
        s[nt] = MFMA16(kb1, qa1, s[nt]);
      }

      const bool nc = (k0 + 63 > base16);
#pragma unroll
      for (int nt = 0; nt < 4; nt++) {
        const int kc4 = k0 + nt * 16 + lg * 4;
        const int4 pd = *reinterpret_cast<const int4*>(&padI[kc4]);
        const int pdv[4] = {pd.x, pd.y, pd.z, pd.w};
#pragma unroll
        for (int i = 0; i < 4; i++) {
          float v = s[nt][i];
          if (pdv[i]) v = NEGV;
          if (nc && (kc4 + i > qrow_l)) v += NEGV;
          s[nt][i] = v;
        }
      }

      float mx = s[0][0];
#pragma unroll
      for (int nt = 0; nt < 4; nt++)
#pragma unroll
        for (int i = 0; i < 4; i++) mx = fmaxf(mx, s[nt][i]);
      mx = fmaxf(mx, __shfl_xor(mx, 16, 64));
      mx = fmaxf(mx, __shfl_xor(mx, 32, 64));

      if (!__all(mx <= m_ - 88.0f)) {          // dynamic underflow skip
        if (!__all(mx <= m_ + 8.0f)) {         // defer-max rescale
          const float mn = fmaxf(m_, mx);
          const float scl = __expf(m_ - mn);
          m_ = mn;
          ld_ *= scl;
#pragma unroll
          for (int nt = 0; nt < 4; nt++) o[nt] *= scl;
        }
        float a = 0.0f;
#pragma unroll
        for (int nt = 0; nt < 4; nt++)
#pragma unroll
          for (int i = 0; i < 4; i++) {
            const float p = __expf(s[nt][i] - m_);
            s[nt][i] = p;
            a += p;
          }
        a += __shfl_xor(a, 16, 64);
        a += __shfl_xor(a, 32, 64);
        ld_ += a;

        bf16x8 pb0, pb1;
        pack_bfly(s, lg, pb0, pb1);

#pragma unroll
        for (int nt = 0; nt < 4; nt++) {
          const int vrow = nt * 16 + lr;
          const int vsw = (vrow & 7) << 4;
          bf16x8 vf0 = *reinterpret_cast<const bf16x8*>(Vb + vrow * 128 + ((lg * 16) ^ vsw));
          bf16x8 vf1 = *reinterpret_cast<const bf16x8*>(Vb + vrow * 128 + ((64 + lg * 16) ^ vsw));
          o[nt] = MFMA16(vf0, pb0, o[nt]);
          o[nt] = MFMA16(vf1, pb1, o[nt]);
        }
      }
    }
    __builtin_amdgcn_s_barrier();  // protect buf[cur] before next prefetch
  }

  // epilogue: o^T[d = nt*16+lg*4+i][q = lr], normalize, 8B vector stores
  const float rinv = 1.0f / ld_;
#pragma unroll
  for (int nt = 0; nt < 4; nt++) {
    bf16x4 rr = {(bf16_t)(o[nt][0] * rinv), (bf16_t)(o[nt][1] * rinv),
                 (bf16_t)(o[nt][2] * rinv), (bf16_t)(o[nt][3] * rinv)};
    *reinterpret_cast<bf16x4*>(outp + (size_t)(b * 1024 + qrow_l) * 1024 + h * 64 + nt * 16 + lg * 4) = rr;
  }
}

// ---------------------------------------------------------------------------
extern "C" void kernel_launch(void* const* d_in, const int* in_sizes, int n_in,
                              void* d_out, int out_size, void* d_ws, size_t ws_size,
                              hipStream_t stream) {
  const float* q   = (const float*)d_in[0];
  const float* k   = (const float*)d_in[1];
  const float* v   = (const float*)d_in[2];
  const int*   pad = (const int*)d_in[3];
  const float* wq  = (const float*)d_in[5];
  const float* bq  = (const float*)d_in[6];
  const float* wk  = (const float*)d_in[7];
  const float* wv  = (const float*)d_in[8];
  const float* bv  = (const float*)d_in[9];
  const float* wo  = (const float*)d_in[10];
  const float* bo  = (const float*)d_in[11];

  char* ws = (char*)d_ws;
  const size_t MiB = 1024 * 1024;
  bf16_t* qbf = (bf16_t*)(ws + 0 * MiB);
  bf16_t* kbf = (bf16_t*)(ws + 16 * MiB);
  bf16_t* vbf = (bf16_t*)(ws + 32 * MiB);
  bf16_t* qp  = (bf16_t*)(ws + 48 * MiB);
  bf16_t* kp  = (bf16_t*)(ws + 64 * MiB);
  bf16_t* vtw = (bf16_t*)(ws + 80 * MiB);
  bf16_t* wqb = (bf16_t*)(ws + 96 * MiB);
  bf16_t* wkb = (bf16_t*)(ws + 98 * MiB);
  bf16_t* wvb = (bf16_t*)(ws + 100 * MiB);
  bf16_t* wob = (bf16_t*)(ws + 102 * MiB);
  bf16_t* attnO = qbf;  // qbf dead after q-projection

  cvt_all<<<14336, 256, 0, stream>>>(q, k, v, wq, wk, wv, wo,
                                     qbf, kbf, vbf, wqb, wkb, wvb, wob);

  gemm_qkv<<<768, 512, 0, stream>>>(qbf, kbf, vbf, wqb, wkb, wvb, bq, bv, qp, kp, vtw);

  attn_fused<<<1024, 512, 0, stream>>>(qp, kp, vtw, pad, attnO);

  gemm_out<<<256, 512, 0, stream>>>(attnO, wob, bo, (float*)d_out);
}

// Round 15
// 171.192 us; speedup vs baseline: 1.1089x; 1.1089x over previous
//
#include <hip/hip_runtime.h>
#include <hip/hip_bf16.h>
#include <cstdint>
#include <math.h>

// ---------------------------------------------------------------------------
// MyMultiHeadAttention: cvt -> q/k/v proj (256x128, BK=32, 3-buf depth-2,
// 72 KiB => 2 blocks/CU, grid=768) -> fused flash attention (r13 paired
// q-tiles + setprio on MFMA clusters) -> output proj (128x128, BK=32, 3-buf,
// 48 KiB => 2 blocks/CU, grid=512).  B=8 S=1024 D=1024 H=16 Dh=64.
// ---------------------------------------------------------------------------

typedef __bf16 bf16_t;
typedef __bf16 bf16x8 __attribute__((ext_vector_type(8)));
typedef __bf16 bf16x4 __attribute__((ext_vector_type(4)));
typedef float  f32x4  __attribute__((ext_vector_type(4)));

#define MFMA16(a, b, c) __builtin_amdgcn_mfma_f32_16x16x32_bf16((a), (b), (c), 0, 0, 0)
#define NEGV (-1e9f)

__device__ __forceinline__ void gl_lds16(const void* gp, void* lp) {
  __builtin_amdgcn_global_load_lds(
      (__attribute__((address_space(1))) void*)(gp),
      (__attribute__((address_space(3))) void*)(lp), 16, 0, 0);
}

// raw barrier with compiler memory fences
__device__ __forceinline__ void bar() {
  asm volatile("" ::: "memory");
  __builtin_amdgcn_s_barrier();
  asm volatile("" ::: "memory");
}

__device__ __forceinline__ unsigned int pk2(float lo, float hi) {
  unsigned short a = __builtin_bit_cast(unsigned short, (bf16_t)lo);
  unsigned short b = __builtin_bit_cast(unsigned short, (bf16_t)hi);
  return (unsigned int)a | ((unsigned int)b << 16);
}

// ---------------- f32 -> bf16 bulk convert, single launch -------------------
__device__ __forceinline__ void cvt_body(const float* __restrict__ in,
                                         bf16_t* __restrict__ out, int i) {
  const float4* p = reinterpret_cast<const float4*>(in) + (size_t)i * 2;
  float4 a = p[0], b = p[1];
  bf16x8 r = {(bf16_t)a.x, (bf16_t)a.y, (bf16_t)a.z, (bf16_t)a.w,
              (bf16_t)b.x, (bf16_t)b.y, (bf16_t)b.z, (bf16_t)b.w};
  *reinterpret_cast<bf16x8*>(out + (size_t)i * 8) = r;
}

__global__ __launch_bounds__(256) void cvt_all(
    const float* __restrict__ q, const float* __restrict__ k, const float* __restrict__ v,
    const float* __restrict__ wq, const float* __restrict__ wk,
    const float* __restrict__ wv, const float* __restrict__ wo,
    bf16_t* __restrict__ oq, bf16_t* __restrict__ ok, bf16_t* __restrict__ ov,
    bf16_t* __restrict__ owq, bf16_t* __restrict__ owk,
    bf16_t* __restrict__ owv, bf16_t* __restrict__ owo) {
  const int bid = (int)blockIdx.x;
  if (bid < 12288) {
    const int s = bid >> 12;
    const int i = (bid & 4095) * 256 + (int)threadIdx.x;
    cvt_body(s == 0 ? q : (s == 1 ? k : v),
             s == 0 ? oq : (s == 1 ? ok : ov), i);
  } else {
    const int r = bid - 12288;
    const int s = r >> 9;
    const int i = (r & 511) * 256 + (int)threadIdx.x;
    cvt_body(s == 0 ? wq : (s == 1 ? wk : (s == 2 ? wv : wo)),
             s == 0 ? owq : (s == 1 ? owk : (s == 2 ? owv : owo)), i);
  }
}

// ============ q/k/v GEMM: 256x128 tile, BK=32, 2 blocks/CU (r13) ============
__global__ __launch_bounds__(512, 4) void gemm_qkv(const bf16_t* __restrict__ qbf,
                                                   const bf16_t* __restrict__ kbf,
                                                   const bf16_t* __restrict__ vbf,
                                                   const bf16_t* __restrict__ wqb,
                                                   const bf16_t* __restrict__ wkb,
                                                   const bf16_t* __restrict__ wvb,
                                                   const float* __restrict__ bq,
                                                   const float* __restrict__ bv,
                                                   bf16_t* __restrict__ qp,
                                                   bf16_t* __restrict__ kp,
                                                   bf16_t* __restrict__ vtw) {
  __shared__ __align__(16) char lds[73728];  // A 3x16K @0, B 3x8K @49152
  const int bid = (int)blockIdx.x;
  const int z = bid >> 8;
  const int idx = bid & 255;
  const int p = ((idx >> 6) << 3) | (idx & 7);
  const int n = (idx >> 3) & 7;
  const bf16_t* A = z == 0 ? qbf : (z == 1 ? kbf : vbf);
  const bf16_t* W = z == 0 ? wqb : (z == 1 ? wkb : wvb);
  const int t = threadIdx.x;
  const int w = t >> 6, l = t & 63, lr = l & 15, lg = l >> 4;
  const int wr = w >> 1, wc = w & 1;
  const int m0 = p * 256, n0 = n * 128;
  const int K = 1024, N = 1024;

  const int gc = (t & 3) ^ ((t >> 3) & 3);
  const bf16_t* Ag = A + (size_t)(m0 + (t >> 2)) * K + gc * 8;
  const bf16_t* Wg = W + (size_t)(n0 + (t >> 2)) * K + gc * 8;

  auto stageA = [&](int buf, int tile) {
    char* dst = lds + buf * 16384 + t * 16;
    const size_t kt = (size_t)tile * 32;
    gl_lds16(Ag + kt,                   dst);
    gl_lds16(Ag + kt + (size_t)128 * K, dst + 8192);
  };
  auto stageB = [&](int buf, int tile) {
    gl_lds16(Wg + (size_t)tile * 32, lds + 49152 + buf * 8192 + t * 16);
  };

  stageA(0, 0); stageB(0, 0); stageA(1, 1); stageB(1, 1);
  asm volatile("s_waitcnt vmcnt(3)" ::: "memory");
  bar();

  f32x4 acc[4][4] = {};
  const int cofs = (lg ^ ((lr >> 1) & 3)) << 4;

  for (int T = 0; T < 32; ++T) {
    const int cur = T % 3;
    const char* Ab = lds + cur * 16384;
    const char* Bb = lds + 49152 + cur * 8192;
    bf16x8 af[4], bfr[4];
#pragma unroll
    for (int mt = 0; mt < 4; mt++)
      af[mt] = *(const bf16x8*)(Ab + (wr * 64 + mt * 16 + lr) * 64 + cofs);
#pragma unroll
    for (int nt = 0; nt < 4; nt++)
      bfr[nt] = *(const bf16x8*)(Bb + (wc * 64 + nt * 16 + lr) * 64 + cofs);
    if (T + 2 < 32) { stageA((T + 2) % 3, T + 2); stageB((T + 2) % 3, T + 2); }
    if (T < 30)       asm volatile("s_waitcnt vmcnt(3)" ::: "memory");
    else if (T == 30) asm volatile("s_waitcnt vmcnt(0)" ::: "memory");
    bar();
    asm volatile("s_waitcnt lgkmcnt(0)" ::: "memory");
    __builtin_amdgcn_s_setprio(1);
#pragma unroll
    for (int mt = 0; mt < 4; mt++)
#pragma unroll
      for (int nt = 0; nt < 4; nt++)
        acc[mt][nt] = MFMA16(af[mt], bfr[nt], acc[mt][nt]);
    __builtin_amdgcn_s_setprio(0);
    bar();
  }

  if (z != 2) {
    bf16_t* outp = (z == 0) ? qp : kp;
    const float sc = (z == 0) ? 0.125f : 1.0f;  // fold attention's /8 (exact)
#pragma unroll
    for (int nt = 0; nt < 4; nt++) {
      const int col = n0 + wc * 64 + nt * 16 + lr;
      const float bb = (z == 0) ? bq[col] : 0.0f;
#pragma unroll
      for (int mt = 0; mt < 4; mt++)
#pragma unroll
        for (int i = 0; i < 4; i++) {
          const int row = m0 + wr * 64 + mt * 16 + lg * 4 + i;
          outp[(size_t)row * N + col] = (bf16_t)((acc[mt][nt][i] + bb) * sc);
        }
    }
  } else {
    __syncthreads();
    char* Tl = lds;
#pragma unroll
    for (int nt = 0; nt < 4; nt++) {
      const int col_l = wc * 64 + nt * 16 + lr;
      const float bb = bv[n0 + col_l];
#pragma unroll
      for (int mt = 0; mt < 4; mt++)
#pragma unroll
        for (int i = 0; i < 4; i++) {
          const int row_l = wr * 64 + mt * 16 + lg * 4 + i;
          *(bf16_t*)(Tl + col_l * 512 + ((row_l * 2) ^ ((col_l & 7) << 4))) =
              (bf16_t)(acc[mt][nt][i] + bb);
        }
    }
    __syncthreads();
    const int b = m0 >> 10, s0 = m0 & 1023;
    const int c_l = t >> 2, sub = t & 3;
    bf16_t* dst = vtw + (size_t)(b * 1024 + n0 + c_l) * 1024 + s0 + sub * 64;
    const char* Trow = Tl + c_l * 512;
    const int sw2 = (c_l & 7) << 4;
#pragma unroll
    for (int jj = 0; jj < 8; jj++) {
      const int lc = sub * 8 + jj;
      bf16x8 vv = *(const bf16x8*)(Trow + ((lc << 4) ^ sw2));
      *(bf16x8*)(dst + jj * 8) = vv;
    }
  }
}

// ---------------- final GEMM: 128x128 tile, BK=32, 2 blocks/CU --------------
// 256 thr = 4 waves (2M x 2N), per-wave 64x64, acc[4][4].  32 K-tiles.
// LDS: A 3x8K @0, B 3x8K @24576 (48 KiB).  Same swizzle/pipeline as gemm_qkv
// (4 stage-calls/tile -> vmcnt(4)).  grid 512 = 64 M-tiles x 8 N-tiles,
// bid%8 == p%8 (A-panel per XCD).
__global__ __launch_bounds__(256, 2) void gemm_out(const bf16_t* __restrict__ A,
                                                   const bf16_t* __restrict__ W,
                                                   const float* __restrict__ bias,
                                                   float* __restrict__ outp) {
  __shared__ __align__(16) char lds[49152];
  const int bid = (int)blockIdx.x;
  const int p = ((bid >> 6) << 3) | (bid & 7);   // M-tile 0..63
  const int n = (bid >> 3) & 7;
  const int t = threadIdx.x;
  const int w = t >> 6, l = t & 63, lr = l & 15, lg = l >> 4;
  const int wr = w >> 1, wc = w & 1;
  const int m0 = p * 128, n0 = n * 128;
  const int K = 1024, N = 1024;

  const int gc = (t & 3) ^ ((t >> 3) & 3);
  const bf16_t* Ag = A + (size_t)(m0 + (t >> 2)) * K + gc * 8;
  const bf16_t* Wg = W + (size_t)(n0 + (t >> 2)) * K + gc * 8;

  auto stageA = [&](int buf, int tile) {
    char* dst = lds + buf * 8192 + t * 16;
    const size_t kt = (size_t)tile * 32;
    gl_lds16(Ag + kt,                  dst);
    gl_lds16(Ag + kt + (size_t)64 * K, dst + 4096);
  };
  auto stageB = [&](int buf, int tile) {
    char* dst = lds + 24576 + buf * 8192 + t * 16;
    const size_t kt = (size_t)tile * 32;
    gl_lds16(Wg + kt,                  dst);
    gl_lds16(Wg + kt + (size_t)64 * K, dst + 4096);
  };

  stageA(0, 0); stageB(0, 0); stageA(1, 1); stageB(1, 1);
  asm volatile("s_waitcnt vmcnt(4)" ::: "memory");
  bar();

  f32x4 acc[4][4] = {};
  const int cofs = (lg ^ ((lr >> 1) & 3)) << 4;

  for (int T = 0; T < 32; ++T) {
    const int cur = T % 3;
    const char* Ab = lds + cur * 8192;
    const char* Bb = lds + 24576 + cur * 8192;
    bf16x8 af[4], bfr[4];
#pragma unroll
    for (int mt = 0; mt < 4; mt++)
      af[mt] = *(const bf16x8*)(Ab + (wr * 64 + mt * 16 + lr) * 64 + cofs);
#pragma unroll
    for (int nt = 0; nt < 4; nt++)
      bfr[nt] = *(const bf16x8*)(Bb + (wc * 64 + nt * 16 + lr) * 64 + cofs);
    if (T + 2 < 32) { stageA((T + 2) % 3, T + 2); stageB((T + 2) % 3, T + 2); }
    if (T < 30)       asm volatile("s_waitcnt vmcnt(4)" ::: "memory");
    else if (T == 30) asm volatile("s_waitcnt vmcnt(0)" ::: "memory");
    bar();
    asm volatile("s_waitcnt lgkmcnt(0)" ::: "memory");
    __builtin_amdgcn_s_setprio(1);
#pragma unroll
    for (int mt = 0; mt < 4; mt++)
#pragma unroll
      for (int nt = 0; nt < 4; nt++)
        acc[mt][nt] = MFMA16(af[mt], bfr[nt], acc[mt][nt]);
    __builtin_amdgcn_s_setprio(0);
    bar();
  }

#pragma unroll
  for (int nt = 0; nt < 4; nt++) {
    const int col = n0 + wc * 64 + nt * 16 + lr;
    const float bb = bias[col];
#pragma unroll
    for (int mt = 0; mt < 4; mt++)
#pragma unroll
      for (int i = 0; i < 4; i++) {
        const int row = m0 + wr * 64 + mt * 16 + lg * 4 + i;
        outp[(size_t)row * N + col] = acc[mt][nt][i] + bb;
      }
  }
}

// ---------------- in-register P pack + butterfly (16-lane groups) ----------
__device__ __forceinline__ void pack_bfly(const f32x4 (&s)[4], int lg,
                                          bf16x8& pbv0, bf16x8& pbv1) {
  unsigned int u[4][2], sh[4][2];
#pragma unroll
  for (int nt = 0; nt < 4; nt++) {
    u[nt][0] = pk2(s[nt][0], s[nt][1]);
    u[nt][1] = pk2(s[nt][2], s[nt][3]);
  }
#pragma unroll
  for (int nt = 0; nt < 4; nt++) {
    sh[nt][0] = (unsigned int)__shfl_xor((int)u[nt][0], 16, 64);
    sh[nt][1] = (unsigned int)__shfl_xor((int)u[nt][1], 16, 64);
  }
  const bool ev = (lg & 1) == 0;
  unsigned int Y[8];
  Y[0] = ev ? u[0][0] : sh[1][0];  Y[1] = ev ? u[0][1] : sh[1][1];
  Y[2] = ev ? u[2][0] : sh[3][0];  Y[3] = ev ? u[2][1] : sh[3][1];
  Y[4] = ev ? sh[0][0] : u[1][0];  Y[5] = ev ? sh[0][1] : u[1][1];
  Y[6] = ev ? sh[2][0] : u[3][0];  Y[7] = ev ? sh[2][1] : u[3][1];
  const bool mid = (lg == 1) || (lg == 2);
#pragma unroll
  for (int j = 0; j < 8; j++) {
    const unsigned int z = (unsigned int)__shfl_xor((int)Y[j], 48, 64);
    Y[j] = mid ? z : Y[j];
  }
  union U8 { unsigned int u[4]; bf16x8 v; };
  U8 p0, p1;
  p0.u[0] = Y[0]; p0.u[1] = Y[1]; p0.u[2] = Y[4]; p0.u[3] = Y[5];
  p1.u[0] = Y[2]; p1.u[1] = Y[3]; p1.u[2] = Y[6]; p1.u[3] = Y[7];
  pbv0 = p0.v;
  pbv1 = p1.v;
}

// ---------------- fused flash attention (r13 paired + setprio) -------------
// Grid 1024: bh = (L&7)+8*(L>>6) (16 bh/XCD), j = (L>>3)&7.
// Block handles q-tiles lo=j (waves 4-7) and hi=15-j (waves 0-3), sharing one
// K/V staging stream over k-tiles 0..hi.  qp pre-scaled by 0.125 (exact).
__global__ __launch_bounds__(512, 8) void attn_fused(const bf16_t* __restrict__ qp,
                                                     const bf16_t* __restrict__ kp,
                                                     const bf16_t* __restrict__ vt,
                                                     const int* __restrict__ pad,
                                                     bf16_t* __restrict__ outp) {
  __shared__ bf16_t Ks[2][64 * 64];   // [key][dh], XOR-swizzled
  __shared__ bf16_t Vts[2][64 * 64];  // [dh][key], XOR-swizzled
  __shared__ int padI[1024];
  __shared__ int sfl[8], sfh[8];
  const int t = threadIdx.x, w = t >> 6, l = t & 63, lr = l & 15, lg = l >> 4;
  const int L = (int)blockIdx.x;
  const int bh = (L & 7) + ((L >> 6) << 3);
  const int j = (L >> 3) & 7;
  const int b = bh >> 4, h = bh & 15;
  const int lo = j, hi = 15 - j;

  const int srow = t >> 3, sc = t & 7;
  const int gc = sc ^ (srow & 7);
  const bf16_t* kgb = kp + (size_t)(b * 1024 + srow) * 1024 + h * 64 + gc * 8;
  const bf16_t* vgb = vt + (size_t)(bh * 64 + srow) * 1024 + gc * 8;

  auto stage = [&](int bufi, int k0s) {
    gl_lds16(kgb + (size_t)k0s * 1024, (char*)(Ks[bufi]) + t * 16);
    gl_lds16(vgb + k0s,                (char*)(Vts[bufi]) + t * 16);
  };

  bool unl = false, unh = false;
  for (int jj = t; jj <= hi * 64; jj += 512) {
    const bool u = (pad[b * 1024 + jj] == 0);
    unh |= u;
    unl |= (u && (jj <= lo * 64));
  }
  const bool al = __any(unl), ah = __any(unh);
  if (l == 0) { sfl[w] = al ? 1 : 0; sfh[w] = ah ? 1 : 0; }

  stage(0, 0);
  if (t < 256) gl_lds16(pad + b * 1024 + t * 4, (char*)padI + t * 16);

  const int mytile = (w < 4) ? hi : lo;
  const int qrow_l = mytile * 64 + (w & 3) * 16 + lr;
  const int base16 = mytile * 64 + (w & 3) * 16;
  const bf16_t* qg = qp + (size_t)(b * 1024 + qrow_l) * 1024 + h * 64 + lg * 8;
  const bf16x8 qa0 = *reinterpret_cast<const bf16x8*>(qg);
  const bf16x8 qa1 = *reinterpret_cast<const bf16x8*>(qg + 32);

  __syncthreads();
  int ul = 0, uh = 0;
#pragma unroll
  for (int i = 0; i < 8; i++) { ul |= sfl[i]; uh |= sfh[i]; }
  const bool mydeg = (w < 4) ? (uh == 0) : (ul == 0);
  const int ktEnd = (ul == 0) ? 16 : (hi + 1);

  f32x4 o[4] = {};
  float m_ = -INFINITY, ld_ = 0.0f;

  for (int kt = 0; kt < ktEnd; ++kt) {
    const int cur = kt & 1;
    if (kt + 1 < ktEnd) {
      stage(cur ^ 1, (kt + 1) * 64);
      asm volatile("s_waitcnt vmcnt(2)" ::: "memory");
    } else {
      asm volatile("s_waitcnt vmcnt(0)" ::: "memory");
    }
    __builtin_amdgcn_s_barrier();

    if (kt <= mytile || mydeg) {
      const char* Kb = (const char*)(Ks[cur]);
      const char* Vb = (const char*)(Vts[cur]);
      const int k0 = kt * 64;

      f32x4 s[4] = {};
      __builtin_amdgcn_s_setprio(1);
#pragma unroll
      for (int nt = 0; nt < 4; nt++) {
        const int row = nt * 16 + lr;
        const int sw = (row & 7) << 4;
        bf16x8 kb0 = *reinterpret_cast<const bf16x8*>(Kb + row * 128 + ((lg * 16) ^ sw));
        bf16x8 kb1 = *reinterpret_cast<const bf16x8*>(Kb + row * 128 + ((lg * 16 + 64) ^ sw));
        s[nt] = MFMA16(kb0, qa0, s[nt]);
        s[nt] = MFMA16(kb1, qa1, s[nt]);
      }
      __builtin_amdgcn_s_setprio(0);

      const bool nc = (k0 + 63 > base16);
#pragma unroll
      for (int nt = 0; nt < 4; nt++) {
        const int kc4 = k0 + nt * 16 + lg * 4;
        const int4 pd = *reinterpret_cast<const int4*>(&padI[kc4]);
        const int pdv[4] = {pd.x, pd.y, pd.z, pd.w};
#pragma unroll
        for (int i = 0; i < 4; i++) {
          float v = s[nt][i];
          if (pdv[i]) v = NEGV;
          if (nc && (kc4 + i > qrow_l)) v += NEGV;
          s[nt][i] = v;
        }
      }

      float mx = s[0][0];
#pragma unroll
      for (int nt = 0; nt < 4; nt++)
#pragma unroll
        for (int i = 0; i < 4; i++) mx = fmaxf(mx, s[nt][i]);
      mx = fmaxf(mx, __shfl_xor(mx, 16, 64));
      mx = fmaxf(mx, __shfl_xor(mx, 32, 64));

      if (!__all(mx <= m_ - 88.0f)) {
        if (!__all(mx <= m_ + 8.0f)) {
          const float mn = fmaxf(m_, mx);
          const float scl = __expf(m_ - mn);
          m_ = mn;
          ld_ *= scl;
#pragma unroll
          for (int nt = 0; nt < 4; nt++) o[nt] *= scl;
        }
        float a = 0.0f;
#pragma unroll
        for (int nt = 0; nt < 4; nt++)
#pragma unroll
          for (int i = 0; i < 4; i++) {
            const float p = __expf(s[nt][i] - m_);
            s[nt][i] = p;
            a += p;
          }
        a += __shfl_xor(a, 16, 64);
        a += __shfl_xor(a, 32, 64);
        ld_ += a;

        bf16x8 pb0, pb1;
        pack_bfly(s, lg, pb0, pb1);

        __builtin_amdgcn_s_setprio(1);
#pragma unroll
        for (int nt = 0; nt < 4; nt++) {
          const int vrow = nt * 16 + lr;
          const int vsw = (vrow & 7) << 4;
          bf16x8 vf0 = *reinterpret_cast<const bf16x8*>(Vb + vrow * 128 + ((lg * 16) ^ vsw));
          bf16x8 vf1 = *reinterpret_cast<const bf16x8*>(Vb + vrow * 128 + ((64 + lg * 16) ^ vsw));
          o[nt] = MFMA16(vf0, pb0, o[nt]);
          o[nt] = MFMA16(vf1, pb1, o[nt]);
        }
        __builtin_amdgcn_s_setprio(0);
      }
    }
    __builtin_amdgcn_s_barrier();
  }

  const float rinv = 1.0f / ld_;
#pragma unroll
  for (int nt = 0; nt < 4; nt++) {
    bf16x4 rr = {(bf16_t)(o[nt][0] * rinv), (bf16_t)(o[nt][1] * rinv),
                 (bf16_t)(o[nt][2] * rinv), (bf16_t)(o[nt][3] * rinv)};
    *reinterpret_cast<bf16x4*>(outp + (size_t)(b * 1024 + qrow_l) * 1024 + h * 64 + nt * 16 + lg * 4) = rr;
  }
}

// ---------------------------------------------------------------------------
extern "C" void kernel_launch(void* const* d_in, const int* in_sizes, int n_in,
                              void* d_out, int out_size, void* d_ws, size_t ws_size,
                              hipStream_t stream) {
  const float* q   = (const float*)d_in[0];
  const float* k   = (const float*)d_in[1];
  const float* v   = (const float*)d_in[2];
  const int*   pad = (const int*)d_in[3];
  const float* wq  = (const float*)d_in[5];
  const float* bq  = (const float*)d_in[6];
  const float* wk  = (const float*)d_in[7];
  const float* wv  = (const float*)d_in[8];
  const float* bv  = (const float*)d_in[9];
  const float* wo  = (const float*)d_in[10];
  const float* bo  = (const float*)d_in[11];

  char* ws = (char*)d_ws;
  const size_t MiB = 1024 * 1024;
  bf16_t* qbf = (bf16_t*)(ws + 0 * MiB);
  bf16_t* kbf = (bf16_t*)(ws + 16 * MiB);
  bf16_t* vbf = (bf16_t*)(ws + 32 * MiB);
  bf16_t* qp  = (bf16_t*)(ws + 48 * MiB);
  bf16_t* kp  = (bf16_t*)(ws + 64 * MiB);
  bf16_t* vtw = (bf16_t*)(ws + 80 * MiB);
  bf16_t* wqb = (bf16_t*)(ws + 96 * MiB);
  bf16_t* wkb = (bf16_t*)(ws + 98 * MiB);
  bf16_t* wvb = (bf16_t*)(ws + 100 * MiB);
  bf16_t* wob = (bf16_t*)(ws + 102 * MiB);
  bf16_t* attnO = qbf;  // qbf dead after q-projection

  cvt_all<<<14336, 256, 0, stream>>>(q, k, v, wq, wk, wv, wo,
                                     qbf, kbf, vbf, wqb, wkb, wvb, wob);

  gemm_qkv<<<768, 512, 0, stream>>>(qbf, kbf, vbf, wqb, wkb, wvb, bq, bv, qp, kp, vtw);

  attn_fused<<<1024, 512, 0, stream>>>(qp, kp, vtw, pad, attnO);

  gemm_out<<<512, 256, 0, stream>>>(attnO, wob, bo, (float*)d_out);
}

// Round 16
// 167.383 us; speedup vs baseline: 1.1342x; 1.0228x over previous
//
#include <hip/hip_runtime.h>
#include <hip/hip_bf16.h>
#include <cstdint>
#include <math.h>

// ---------------------------------------------------------------------------
// MyMultiHeadAttention: cvt (weights only) -> q/k/v proj reading f32 A
// directly (128x128, BK=32, f32-LDS staging via gl_lds, cvt at frag read,
// 3-buf depth-2 counted vmcnt, 72 KiB => 2 blocks/CU, grid=1536=3 rounds)
// -> fused flash attention (paired q-tiles + setprio) -> output proj
// (128x128, BK=32, 48 KiB, grid=512).  B=8 S=1024 D=1024 H=16 Dh=64.
// ---------------------------------------------------------------------------

typedef __bf16 bf16_t;
typedef __bf16 bf16x8 __attribute__((ext_vector_type(8)));
typedef __bf16 bf16x4 __attribute__((ext_vector_type(4)));
typedef float  f32x4  __attribute__((ext_vector_type(4)));

#define MFMA16(a, b, c) __builtin_amdgcn_mfma_f32_16x16x32_bf16((a), (b), (c), 0, 0, 0)
#define NEGV (-1e9f)

__device__ __forceinline__ void gl_lds16(const void* gp, void* lp) {
  __builtin_amdgcn_global_load_lds(
      (__attribute__((address_space(1))) void*)(gp),
      (__attribute__((address_space(3))) void*)(lp), 16, 0, 0);
}

// raw barrier with compiler memory fences
__device__ __forceinline__ void bar() {
  asm volatile("" ::: "memory");
  __builtin_amdgcn_s_barrier();
  asm volatile("" ::: "memory");
}

__device__ __forceinline__ unsigned int pk2(float lo, float hi) {
  unsigned short a = __builtin_bit_cast(unsigned short, (bf16_t)lo);
  unsigned short b = __builtin_bit_cast(unsigned short, (bf16_t)hi);
  return (unsigned int)a | ((unsigned int)b << 16);
}

// ---------------- f32 -> bf16 weight convert (weights only) -----------------
__device__ __forceinline__ void cvt_body(const float* __restrict__ in,
                                         bf16_t* __restrict__ out, int i) {
  const float4* p = reinterpret_cast<const float4*>(in) + (size_t)i * 2;
  float4 a = p[0], b = p[1];
  bf16x8 r = {(bf16_t)a.x, (bf16_t)a.y, (bf16_t)a.z, (bf16_t)a.w,
              (bf16_t)b.x, (bf16_t)b.y, (bf16_t)b.z, (bf16_t)b.w};
  *reinterpret_cast<bf16x8*>(out + (size_t)i * 8) = r;
}

__global__ __launch_bounds__(256) void cvt_w(
    const float* __restrict__ wq, const float* __restrict__ wk,
    const float* __restrict__ wv, const float* __restrict__ wo,
    bf16_t* __restrict__ owq, bf16_t* __restrict__ owk,
    bf16_t* __restrict__ owv, bf16_t* __restrict__ owo) {
  const int bid = (int)blockIdx.x;
  const int s = bid >> 9;
  const int i = (bid & 511) * 256 + (int)threadIdx.x;
  cvt_body(s == 0 ? wq : (s == 1 ? wk : (s == 2 ? wv : wo)),
           s == 0 ? owq : (s == 1 ? owk : (s == 2 ? owv : owo)), i);
}

// ============ q/k/v GEMM: 128x128 tile, BK=32, f32 A staged direct ==========
// 256 thr = 4 waves (2M x 2N), per-wave 64x64, acc[4][4], 32 K-tiles.
// LDS: A-f32 3 x 16 KiB @0, B-bf16 3 x 8 KiB @49152 (72 KiB => 2 blocks/CU).
// A stored f32, LDS[r][c16B] = global 4-f32 chunk c ^ (r&7) (pre-swizzled
// source, linear gl_lds dest); frags read as 2x f32x4 + 8 casts (same RNE
// rounding as the old cvt pass -> bit-identical).  B: bf16, chunk c ^
// ((r>>1)&3) (r13-proven).  Depth-2: 6 stage-calls/tile, vmcnt(6) retires
// exactly tile T+1 BEFORE the barrier (r10-proven ordering).
// grid 1536: z = bid>>9; idx = bid&511 -> p = ((idx>>6)<<3)|(idx&7) (0..63,
// p%8==XCD), n = (idx>>3)&7 (8 N-tiles share p's XCD -> f32 A panel L2-res).
__global__ __launch_bounds__(256, 2) void gemm_qkv(const float* __restrict__ qf,
                                                   const float* __restrict__ kf,
                                                   const float* __restrict__ vf,
                                                   const bf16_t* __restrict__ wqb,
                                                   const bf16_t* __restrict__ wkb,
                                                   const bf16_t* __restrict__ wvb,
                                                   const float* __restrict__ bq,
                                                   const float* __restrict__ bv,
                                                   bf16_t* __restrict__ qp,
                                                   bf16_t* __restrict__ kp,
                                                   bf16_t* __restrict__ vtw) {
  __shared__ __align__(16) char lds[73728];  // A-f32 3x16K @0, B 3x8K @49152
  const int bid = (int)blockIdx.x;
  const int z = bid >> 9;
  const int idx = bid & 511;
  const int p = ((idx >> 6) << 3) | (idx & 7);   // M-tile 0..63
  const int n = (idx >> 3) & 7;
  const float*  A = z == 0 ? qf : (z == 1 ? kf : vf);
  const bf16_t* W = z == 0 ? wqb : (z == 1 ? wkb : wvb);
  const int t = threadIdx.x;
  const int w = t >> 6, l = t & 63, lr = l & 15, lg = l >> 4;
  const int wr = w >> 1, wc = w & 1;
  const int m0 = p * 128, n0 = n * 128;
  const int K = 1024, N = 1024;

  // A staging: call c covers rows [32c,32c+32); thread t -> row (t>>3),
  // linear chunk t&7; source chunk pre-swizzled (row&7 == (t>>3)&7).
  const int gcA = (t & 7) ^ ((t >> 3) & 7);
  const float* Ag = A + (size_t)(m0 + (t >> 3)) * K + gcA * 4;
  // B staging: rows t>>2 and +64, chunk t&3, source pre-swizzled.
  const int gcB = (t & 3) ^ ((t >> 3) & 3);
  const bf16_t* Wg = W + (size_t)(n0 + (t >> 2)) * K + gcB * 8;

  auto stageA = [&](int buf, int tile) {
    char* dst = lds + buf * 16384 + t * 16;
    const size_t kt = (size_t)tile * 32;
#pragma unroll
    for (int c = 0; c < 4; c++)
      gl_lds16(Ag + (size_t)(c * 32) * K + kt, dst + c * 4096);
  };
  auto stageB = [&](int buf, int tile) {
    char* dst = lds + 49152 + buf * 8192 + t * 16;
    const size_t kt = (size_t)tile * 32;
    gl_lds16(Wg + kt,                  dst);
    gl_lds16(Wg + kt + (size_t)64 * K, dst + 4096);
  };

  stageA(0, 0); stageB(0, 0); stageA(1, 1); stageB(1, 1);
  asm volatile("s_waitcnt vmcnt(6)" ::: "memory");  // tile 0 landed (own)
  bar();

  f32x4 acc[4][4] = {};
  const int cofsB = (lg ^ ((lr >> 1) & 3)) << 4;

  for (int T = 0; T < 32; ++T) {
    const int cur = T % 3;
    const char* Ab = lds + cur * 16384;
    const char* Bb = lds + 49152 + cur * 8192;
    bf16x8 af[4], bfr[4];
#pragma unroll
    for (int mt = 0; mt < 4; mt++) {
      const int R = wr * 64 + mt * 16 + lr;
      const int sw = R & 7;
      f32x4 a0 = *(const f32x4*)(Ab + R * 128 + (((2 * lg) ^ sw) << 4));
      f32x4 a1 = *(const f32x4*)(Ab + R * 128 + (((2 * lg + 1) ^ sw) << 4));
      af[mt] = (bf16x8){(bf16_t)a0[0], (bf16_t)a0[1], (bf16_t)a0[2], (bf16_t)a0[3],
                        (bf16_t)a1[0], (bf16_t)a1[1], (bf16_t)a1[2], (bf16_t)a1[3]};
    }
#pragma unroll
    for (int nt = 0; nt < 4; nt++)
      bfr[nt] = *(const bf16x8*)(Bb + (wc * 64 + nt * 16 + lr) * 64 + cofsB);
    if (T + 2 < 32) { stageA((T + 2) % 3, T + 2); stageB((T + 2) % 3, T + 2); }
    if (T < 30)       asm volatile("s_waitcnt vmcnt(6)" ::: "memory");
    else if (T == 30) asm volatile("s_waitcnt vmcnt(0)" ::: "memory");
    bar();  // tile T+1 landed chip-wide
    asm volatile("s_waitcnt lgkmcnt(0)" ::: "memory");
    __builtin_amdgcn_s_setprio(1);
#pragma unroll
    for (int mt = 0; mt < 4; mt++)
#pragma unroll
      for (int nt = 0; nt < 4; nt++)
        acc[mt][nt] = MFMA16(af[mt], bfr[nt], acc[mt][nt]);
    __builtin_amdgcn_s_setprio(0);
    bar();
  }

  if (z != 2) {
    bf16_t* outp = (z == 0) ? qp : kp;
    const float sc = (z == 0) ? 0.125f : 1.0f;  // fold attention's /8 (exact)
#pragma unroll
    for (int nt = 0; nt < 4; nt++) {
      const int col = n0 + wc * 64 + nt * 16 + lr;
      const float bb = (z == 0) ? bq[col] : 0.0f;
#pragma unroll
      for (int mt = 0; mt < 4; mt++)
#pragma unroll
        for (int i = 0; i < 4; i++) {
          const int row = m0 + wr * 64 + mt * 16 + lg * 4 + i;
          outp[(size_t)row * N + col] = (bf16_t)((acc[mt][nt][i] + bb) * sc);
        }
    }
  } else {
    // vt epilogue (r6-verified 128x128 bounce): C^T -> LDS swizzled -> coal.
    __syncthreads();
    char* Tl = lds;
#pragma unroll
    for (int nt = 0; nt < 4; nt++) {
      const int col_l = wc * 64 + nt * 16 + lr;           // 0..127
      const float bb = bv[n0 + col_l];
#pragma unroll
      for (int mt = 0; mt < 4; mt++)
#pragma unroll
        for (int i = 0; i < 4; i++) {
          const int row_l = wr * 64 + mt * 16 + lg * 4 + i;  // 0..127
          *(bf16_t*)(Tl + col_l * 256 + ((row_l * 2) ^ ((col_l & 7) << 4))) =
              (bf16_t)(acc[mt][nt][i] + bb);
        }
    }
    __syncthreads();
    const int b = m0 >> 10, s0 = m0 & 1023;
    const int c_l = t >> 1, half = t & 1;
    bf16_t* dst = vtw + (size_t)(b * 1024 + n0 + c_l) * 1024 + s0 + half * 64;
    const char* Trow = Tl + c_l * 256;
    const int sw = c_l & 7;
#pragma unroll
    for (int jj = 0; jj < 8; jj++) {
      const int lc = half * 8 + jj;
      bf16x8 vv = *(const bf16x8*)(Trow + ((lc ^ sw) << 4));
      *(bf16x8*)(dst + jj * 8) = vv;
    }
  }
}

// ---------------- final GEMM: 128x128 tile, BK=32, 2 blocks/CU (r15) --------
__global__ __launch_bounds__(256, 2) void gemm_out(const bf16_t* __restrict__ A,
                                                   const bf16_t* __restrict__ W,
                                                   const float* __restrict__ bias,
                                                   float* __restrict__ outp) {
  __shared__ __align__(16) char lds[49152];
  const int bid = (int)blockIdx.x;
  const int p = ((bid >> 6) << 3) | (bid & 7);   // M-tile 0..63
  const int n = (bid >> 3) & 7;
  const int t = threadIdx.x;
  const int w = t >> 6, l = t & 63, lr = l & 15, lg = l >> 4;
  const int wr = w >> 1, wc = w & 1;
  const int m0 = p * 128, n0 = n * 128;
  const int K = 1024, N = 1024;

  const int gc = (t & 3) ^ ((t >> 3) & 3);
  const bf16_t* Ag = A + (size_t)(m0 + (t >> 2)) * K + gc * 8;
  const bf16_t* Wg = W + (size_t)(n0 + (t >> 2)) * K + gc * 8;

  auto stageA = [&](int buf, int tile) {
    char* dst = lds + buf * 8192 + t * 16;
    const size_t kt = (size_t)tile * 32;
    gl_lds16(Ag + kt,                  dst);
    gl_lds16(Ag + kt + (size_t)64 * K, dst + 4096);
  };
  auto stageB = [&](int buf, int tile) {
    char* dst = lds + 24576 + buf * 8192 + t * 16;
    const size_t kt = (size_t)tile * 32;
    gl_lds16(Wg + kt,                  dst);
    gl_lds16(Wg + kt + (size_t)64 * K, dst + 4096);
  };

  stageA(0, 0); stageB(0, 0); stageA(1, 1); stageB(1, 1);
  asm volatile("s_waitcnt vmcnt(4)" ::: "memory");
  bar();

  f32x4 acc[4][4] = {};
  const int cofs = (lg ^ ((lr >> 1) & 3)) << 4;

  for (int T = 0; T < 32; ++T) {
    const int cur = T % 3;
    const char* Ab = lds + cur * 8192;
    const char* Bb = lds + 24576 + cur * 8192;
    bf16x8 af[4], bfr[4];
#pragma unroll
    for (int mt = 0; mt < 4; mt++)
      af[mt] = *(const bf16x8*)(Ab + (wr * 64 + mt * 16 + lr) * 64 + cofs);
#pragma unroll
    for (int nt = 0; nt < 4; nt++)
      bfr[nt] = *(const bf16x8*)(Bb + (wc * 64 + nt * 16 + lr) * 64 + cofs);
    if (T + 2 < 32) { stageA((T + 2) % 3, T + 2); stageB((T + 2) % 3, T + 2); }
    if (T < 30)       asm volatile("s_waitcnt vmcnt(4)" ::: "memory");
    else if (T == 30) asm volatile("s_waitcnt vmcnt(0)" ::: "memory");
    bar();
    asm volatile("s_waitcnt lgkmcnt(0)" ::: "memory");
    __builtin_amdgcn_s_setprio(1);
#pragma unroll
    for (int mt = 0; mt < 4; mt++)
#pragma unroll
      for (int nt = 0; nt < 4; nt++)
        acc[mt][nt] = MFMA16(af[mt], bfr[nt], acc[mt][nt]);
    __builtin_amdgcn_s_setprio(0);
    bar();
  }

#pragma unroll
  for (int nt = 0; nt < 4; nt++) {
    const int col = n0 + wc * 64 + nt * 16 + lr;
    const float bb = bias[col];
#pragma unroll
    for (int mt = 0; mt < 4; mt++)
#pragma unroll
      for (int i = 0; i < 4; i++) {
        const int row = m0 + wr * 64 + mt * 16 + lg * 4 + i;
        outp[(size_t)row * N + col] = acc[mt][nt][i] + bb;
      }
  }
}

// ---------------- in-register P pack + butterfly (16-lane groups) ----------
__device__ __forceinline__ void pack_bfly(const f32x4 (&s)[4], int lg,
                                          bf16x8& pbv0, bf16x8& pbv1) {
  unsigned int u[4][2], sh[4][2];
#pragma unroll
  for (int nt = 0; nt < 4; nt++) {
    u[nt][0] = pk2(s[nt][0], s[nt][1]);
    u[nt][1] = pk2(s[nt][2], s[nt][3]);
  }
#pragma unroll
  for (int nt = 0; nt < 4; nt++) {
    sh[nt][0] = (unsigned int)__shfl_xor((int)u[nt][0], 16, 64);
    sh[nt][1] = (unsigned int)__shfl_xor((int)u[nt][1], 16, 64);
  }
  const bool ev = (lg & 1) == 0;
  unsigned int Y[8];
  Y[0] = ev ? u[0][0] : sh[1][0];  Y[1] = ev ? u[0][1] : sh[1][1];
  Y[2] = ev ? u[2][0] : sh[3][0];  Y[3] = ev ? u[2][1] : sh[3][1];
  Y[4] = ev ? sh[0][0] : u[1][0];  Y[5] = ev ? sh[0][1] : u[1][1];
  Y[6] = ev ? sh[2][0] : u[3][0];  Y[7] = ev ? sh[2][1] : u[3][1];
  const bool mid = (lg == 1) || (lg == 2);
#pragma unroll
  for (int j = 0; j < 8; j++) {
    const unsigned int z = (unsigned int)__shfl_xor((int)Y[j], 48, 64);
    Y[j] = mid ? z : Y[j];
  }
  union U8 { unsigned int u[4]; bf16x8 v; };
  U8 p0, p1;
  p0.u[0] = Y[0]; p0.u[1] = Y[1]; p0.u[2] = Y[4]; p0.u[3] = Y[5];
  p1.u[0] = Y[2]; p1.u[1] = Y[3]; p1.u[2] = Y[6]; p1.u[3] = Y[7];
  pbv0 = p0.v;
  pbv1 = p1.v;
}

// ---------------- fused flash attention (r15 paired + setprio) -------------
__global__ __launch_bounds__(512, 8) void attn_fused(const bf16_t* __restrict__ qp,
                                                     const bf16_t* __restrict__ kp,
                                                     const bf16_t* __restrict__ vt,
                                                     const int* __restrict__ pad,
                                                     bf16_t* __restrict__ outp) {
  __shared__ bf16_t Ks[2][64 * 64];   // [key][dh], XOR-swizzled
  __shared__ bf16_t Vts[2][64 * 64];  // [dh][key], XOR-swizzled
  __shared__ int padI[1024];
  __shared__ int sfl[8], sfh[8];
  const int t = threadIdx.x, w = t >> 6, l = t & 63, lr = l & 15, lg = l >> 4;
  const int L = (int)blockIdx.x;
  const int bh = (L & 7) + ((L >> 6) << 3);
  const int j = (L >> 3) & 7;
  const int b = bh >> 4, h = bh & 15;
  const int lo = j, hi = 15 - j;

  const int srow = t >> 3, sc = t & 7;
  const int gc = sc ^ (srow & 7);
  const bf16_t* kgb = kp + (size_t)(b * 1024 + srow) * 1024 + h * 64 + gc * 8;
  const bf16_t* vgb = vt + (size_t)(bh * 64 + srow) * 1024 + gc * 8;

  auto stage = [&](int bufi, int k0s) {
    gl_lds16(kgb + (size_t)k0s * 1024, (char*)(Ks[bufi]) + t * 16);
    gl_lds16(vgb + k0s,                (char*)(Vts[bufi]) + t * 16);
  };

  bool unl = false, unh = false;
  for (int jj = t; jj <= hi * 64; jj += 512) {
    const bool u = (pad[b * 1024 + jj] == 0);
    unh |= u;
    unl |= (u && (jj <= lo * 64));
  }
  const bool al = __any(unl), ah = __any(unh);
  if (l == 0) { sfl[w] = al ? 1 : 0; sfh[w] = ah ? 1 : 0; }

  stage(0, 0);
  if (t < 256) gl_lds16(pad + b * 1024 + t * 4, (char*)padI + t * 16);

  const int mytile = (w < 4) ? hi : lo;
  const int qrow_l = mytile * 64 + (w & 3) * 16 + lr;
  const int base16 = mytile * 64 + (w & 3) * 16;
  const bf16_t* qg = qp + (size_t)(b * 1024 + qrow_l) * 1024 + h * 64 + lg * 8;
  const bf16x8 qa0 = *reinterpret_cast<const bf16x8*>(qg);
  const bf16x8 qa1 = *reinterpret_cast<const bf16x8*>(qg + 32);

  __syncthreads();
  int ul = 0, uh = 0;
#pragma unroll
  for (int i = 0; i < 8; i++) { ul |= sfl[i]; uh |= sfh[i]; }
  const bool mydeg = (w < 4) ? (uh == 0) : (ul == 0);
  const int ktEnd = (ul == 0) ? 16 : (hi + 1);

  f32x4 o[4] = {};
  float m_ = -INFINITY, ld_ = 0.0f;

  for (int kt = 0; kt < ktEnd; ++kt) {
    const int cur = kt & 1;
    if (kt + 1 < ktEnd) {
      stage(cur ^ 1, (kt + 1) * 64);
      asm volatile("s_waitcnt vmcnt(2)" ::: "memory");
    } else {
      asm volatile("s_waitcnt vmcnt(0)" ::: "memory");
    }
    __builtin_amdgcn_s_barrier();

    if (kt <= mytile || mydeg) {
      const char* Kb = (const char*)(Ks[cur]);
      const char* Vb = (const char*)(Vts[cur]);
      const int k0 = kt * 64;

      f32x4 s[4] = {};
      __builtin_amdgcn_s_setprio(1);
#pragma unroll
      for (int nt = 0; nt < 4; nt++) {
        const int row = nt * 16 + lr;
        const int sw = (row & 7) << 4;
        bf16x8 kb0 = *reinterpret_cast<const bf16x8*>(Kb + row * 128 + ((lg * 16) ^ sw));
        bf16x8 kb1 = *reinterpret_cast<const bf16x8*>(Kb + row * 128 + ((lg * 16 + 64) ^ sw));
        s[nt] = MFMA16(kb0, qa0, s[nt]);
        s[nt] = MFMA16(kb1, qa1, s[nt]);
      }
      __builtin_amdgcn_s_setprio(0);

      const bool nc = (k0 + 63 > base16);
#pragma unroll
      for (int nt = 0; nt < 4; nt++) {
        const int kc4 = k0 + nt * 16 + lg * 4;
        const int4 pd = *reinterpret_cast<const int4*>(&padI[kc4]);
        const int pdv[4] = {pd.x, pd.y, pd.z, pd.w};
#pragma unroll
        for (int i = 0; i < 4; i++) {
          float v = s[nt][i];
          if (pdv[i]) v = NEGV;
          if (nc && (kc4 + i > qrow_l)) v += NEGV;
          s[nt][i] = v;
        }
      }

      float mx = s[0][0];
#pragma unroll
      for (int nt = 0; nt < 4; nt++)
#pragma unroll
        for (int i = 0; i < 4; i++) mx = fmaxf(mx, s[nt][i]);
      mx = fmaxf(mx, __shfl_xor(mx, 16, 64));
      mx = fmaxf(mx, __shfl_xor(mx, 32, 64));

      if (!__all(mx <= m_ - 88.0f)) {
        if (!__all(mx <= m_ + 8.0f)) {
          const float mn = fmaxf(m_, mx);
          const float scl = __expf(m_ - mn);
          m_ = mn;
          ld_ *= scl;
#pragma unroll
          for (int nt = 0; nt < 4; nt++) o[nt] *= scl;
        }
        float a = 0.0f;
#pragma unroll
        for (int nt = 0; nt < 4; nt++)
#pragma unroll
          for (int i = 0; i < 4; i++) {
            const float p = __expf(s[nt][i] - m_);
            s[nt][i] = p;
            a += p;
          }
        a += __shfl_xor(a, 16, 64);
        a += __shfl_xor(a, 32, 64);
        ld_ += a;

        bf16x8 pb0, pb1;
        pack_bfly(s, lg, pb0, pb1);

        __builtin_amdgcn_s_setprio(1);
#pragma unroll
        for (int nt = 0; nt < 4; nt++) {
          const int vrow = nt * 16 + lr;
          const int vsw = (vrow & 7) << 4;
          bf16x8 vf0 = *reinterpret_cast<const bf16x8*>(Vb + vrow * 128 + ((lg * 16) ^ vsw));
          bf16x8 vf1 = *reinterpret_cast<const bf16x8*>(Vb + vrow * 128 + ((64 + lg * 16) ^ vsw));
          o[nt] = MFMA16(vf0, pb0, o[nt]);
          o[nt] = MFMA16(vf1, pb1, o[nt]);
        }
        __builtin_amdgcn_s_setprio(0);
      }
    }
    __builtin_amdgcn_s_barrier();
  }

  const float rinv = 1.0f / ld_;
#pragma unroll
  for (int nt = 0; nt < 4; nt++) {
    bf16x4 rr = {(bf16_t)(o[nt][0] * rinv), (bf16_t)(o[nt][1] * rinv),
                 (bf16_t)(o[nt][2] * rinv), (bf16_t)(o[nt][3] * rinv)};
    *reinterpret_cast<bf16x4*>(outp + (size_t)(b * 1024 + qrow_l) * 1024 + h * 64 + nt * 16 + lg * 4) = rr;
  }
}

// ---------------------------------------------------------------------------
extern "C" void kernel_launch(void* const* d_in, const int* in_sizes, int n_in,
                              void* d_out, int out_size, void* d_ws, size_t ws_size,
                              hipStream_t stream) {
  const float* q   = (const float*)d_in[0];
  const float* k   = (const float*)d_in[1];
  const float* v   = (const float*)d_in[2];
  const int*   pad = (const int*)d_in[3];
  const float* wq  = (const float*)d_in[5];
  const float* bq  = (const float*)d_in[6];
  const float* wk  = (const float*)d_in[7];
  const float* wv  = (const float*)d_in[8];
  const float* bv  = (const float*)d_in[9];
  const float* wo  = (const float*)d_in[10];
  const float* bo  = (const float*)d_in[11];

  char* ws = (char*)d_ws;
  const size_t MiB = 1024 * 1024;
  bf16_t* attnO = (bf16_t*)(ws + 0 * MiB);   // 16 MiB
  bf16_t* qp  = (bf16_t*)(ws + 48 * MiB);
  bf16_t* kp  = (bf16_t*)(ws + 64 * MiB);
  bf16_t* vtw = (bf16_t*)(ws + 80 * MiB);
  bf16_t* wqb = (bf16_t*)(ws + 96 * MiB);
  bf16_t* wkb = (bf16_t*)(ws + 98 * MiB);
  bf16_t* wvb = (bf16_t*)(ws + 100 * MiB);
  bf16_t* wob = (bf16_t*)(ws + 102 * MiB);

  cvt_w<<<2048, 256, 0, stream>>>(wq, wk, wv, wo, wqb, wkb, wvb, wob);

  gemm_qkv<<<1536, 256, 0, stream>>>(q, k, v, wqb, wkb, wvb, bq, bv, qp, kp, vtw);

  attn_fused<<<1024, 512, 0, stream>>>(qp, kp, vtw, pad, attnO);

  gemm_out<<<512, 256, 0, stream>>>(attnO, wob, bo, (float*)d_out);
}